// Round 3
// baseline (94.919 us; speedup 1.0000x reference)
//
#include <hip/hip_runtime.h>

// QuantLinearMarlin: out[16,8192] = x[16,8192] @ dequant(qweight[1024,8192], scales[64,8192]) + bias
//   dequant: w[k,n] = (nibble(qweight[k/8,n], k%8) - 8) * scales[k/128, n]
// Harness dtypes: fp16 reference canonicalized to f32 -> x/scales/bias/out are float*.
//
// Round 3: fix DRAM granularity. Round 2 read qweight as scattered 128 B granules
// (0.9 TB/s effective). Now: block = 256-col x 512-k tile; stage 64 KB of qweight to
// LDS with 1 KB-contiguous wave loads (64 lanes x dwordx4), pre-swizzled into MFMA
// B-fragment order (consumer read = base + lane, conflict-free ds_read_b32).
// Grid 512 = 32 N-tiles x 16 K-splits (2 blocks/CU: stage/compute overlap).
// Cross-block K reduction: f32 unsafeAtomicAdd onto bias-prefilled out.

#define K_DIM 8192
#define N_DIM 8192

typedef _Float16 h2 __attribute__((ext_vector_type(2)));
typedef _Float16 h8 __attribute__((ext_vector_type(8)));
typedef float f32x4 __attribute__((ext_vector_type(4)));
union H8U { unsigned u[4]; h8 h; };

__device__ __forceinline__ unsigned pkrtz_u(float a, float b) {
  return __builtin_bit_cast(unsigned, __builtin_amdgcn_cvt_pkrtz(a, b));
}

__global__ void bias_init_kernel(const float* __restrict__ bias, float* __restrict__ out) {
  int i = blockIdx.x * 256 + threadIdx.x;  // 512 blocks x 256 = 131072 = 16*8192
  out[i] = bias[i & (N_DIM - 1)];
}

__global__ __launch_bounds__(512, 4) void qlin_main(
    const float* __restrict__ x,       // [16][8192]
    const int* __restrict__ qw,        // [1024][8192]
    const float* __restrict__ scales,  // [64][8192]
    float* __restrict__ out) {         // [16][8192], pre-filled with bias
  __shared__ int lds_q[16384];  // 64 KB; reused as float red[2][16][256] in epilogue

  const int tid = threadIdx.x;
  const int ntb = blockIdx.x & 31;   // N-tile 0..31
  const int ksb = blockIdx.x >> 5;   // K-split 0..15
  const int nb = ntb << 8;           // col base
  const int kb = ksb << 9;           // k base (512 per block)
  const int rowbase = ksb << 6;      // qw row base (64 rows per block)

  // ---- stage qweight tile (64 rows x 256 cols) into LDS, fragment order ----
  // global: wave reads 1 KB contiguous (one full tile-row) per instruction.
  // LDS word index L(row,col) = ((row>>2)*16 + (col>>4))*64 + (row&3)*16 + (col&15)
  //   -> consumer (quad q=row&3, lane-col c=col&15) reads base+lane, conflict-free.
  const int* qg = qw + (size_t)rowbase * N_DIM + nb;
  int4 v[8];
#pragma unroll
  for (int p = 0; p < 8; ++p) {
    int idx = (p << 9) + tid;        // int4 index in tile (4096 total)
    int row = idx >> 6;              // 0..63
    int c4 = (idx & 63) << 2;        // col 0..252 step 4
    v[p] = *(const int4*)(qg + (size_t)row * N_DIM + c4);
  }
#pragma unroll
  for (int p = 0; p < 8; ++p) {
    int idx = (p << 9) + tid;
    int row = idx >> 6;
    int c4 = (idx & 63) << 2;
    int L = (((row >> 2) << 4) + (c4 >> 4)) * 64 + ((row & 3) << 4) + (c4 & 15);
    *(int4*)&lds_q[L] = v[p];        // c4&15 in {0,4,8,12} -> 16B aligned
  }
  __syncthreads();

  // ---- compute: wave (wn,wk): cols wn*64..+63, k-sub wk*256..+255 ----
  const int wave = tid >> 6, lane = tid & 63;
  const int wn = wave & 3, wk = wave >> 2;
  const int c = lane & 15, q = lane >> 4;

  // per-group fp16 scales (k-groups of 128: 2 per wave k-sub), 4 col-tiles
  h2 sc[2][4];
#pragma unroll
  for (int g2 = 0; g2 < 2; ++g2)
#pragma unroll
    for (int ct = 0; ct < 4; ++ct) {
      float sv = scales[(size_t)((ksb << 2) + (wk << 1) + g2) * N_DIM +
                        nb + (wn << 6) + (ct << 4) + c];
      sc[g2][ct] = __builtin_bit_cast(h2, pkrtz_u(sv, sv));  // exact (orig fp16)
    }

  const h2 koff = __builtin_bit_cast(h2, 0x64086408u);  // (1032.0h, 1032.0h)
  f32x4 acc[4] = {{0.f,0.f,0.f,0.f},{0.f,0.f,0.f,0.f},{0.f,0.f,0.f,0.f},{0.f,0.f,0.f,0.f}};

  // A: x[m=c][kb + wk*256 + s*32 + q*8 + j], packed in (j, j+4) pair order
  const float* xp = x + (size_t)c * K_DIM + kb + (wk << 8) + (q << 3);
#pragma unroll
  for (int s = 0; s < 8; ++s) {
    float4 xa = *(const float4*)xp;
    float4 xb = *(const float4*)(xp + 4);
    xp += 32;
    H8U a;
    a.u[0] = pkrtz_u(xa.x, xb.x);
    a.u[1] = pkrtz_u(xa.y, xb.y);
    a.u[2] = pkrtz_u(xa.z, xb.z);
    a.u[3] = pkrtz_u(xa.w, xb.w);
    int base = ((((wk << 3) + s) << 4) + (wn << 2)) * 64 + lane;
#pragma unroll
    for (int ct = 0; ct < 4; ++ct) {
      unsigned qv = (unsigned)lds_q[base + (ct << 6)];
      h2 s2 = sc[s >> 2][ct];
      H8U b;
#pragma unroll
      for (int p = 0; p < 4; ++p) {
        unsigned t = ((qv >> (4 * p)) & 0x000F000Fu) | 0x64006400u;
        h2 w = (__builtin_bit_cast(h2, t) - koff) * s2;  // (nib-8) exact, then *s RTN
        b.u[p] = __builtin_bit_cast(unsigned, w);
      }
      acc[ct] = __builtin_amdgcn_mfma_f32_16x16x32_f16(a.h, b.h, acc[ct], 0, 0, 0);
    }
  }

  // ---- epilogue: reduce wk pairs through LDS, then one atomicAdd per output ----
  __syncthreads();  // done reading lds_q as qweight
  float* red = (float*)lds_q;  // [2][16][256]
#pragma unroll
  for (int ct = 0; ct < 4; ++ct)
#pragma unroll
    for (int r = 0; r < 4; ++r)
      red[((wk << 4) + (q << 2) + r) * 256 + (wn << 6) + (ct << 4) + c] = acc[ct][r];
  __syncthreads();

#pragma unroll
  for (int e = 0; e < 8; ++e) {
    int idx = (e << 9) + tid;  // 0..4095
    int m = idx >> 8, j = idx & 255;
    float vv = red[m * 256 + j] + red[(16 + m) * 256 + j];
    unsafeAtomicAdd(&out[(size_t)m * N_DIM + nb + j], vv);  // global_atomic_add_f32
  }
}

extern "C" void kernel_launch(void* const* d_in, const int* in_sizes, int n_in,
                              void* d_out, int out_size, void* d_ws, size_t ws_size,
                              hipStream_t stream) {
  const float* x      = (const float*)d_in[0];  // [16,8192] f32
  const int* qw       = (const int*)d_in[1];    // [1024,8192] i32
  const float* scales = (const float*)d_in[2];  // [64,8192] f32
  const float* bias   = (const float*)d_in[3];  // [8192] f32
  float* out          = (float*)d_out;          // [16,8192] f32

  bias_init_kernel<<<512, 256, 0, stream>>>(bias, out);
  qlin_main<<<512, 512, 0, stream>>>(x, qw, scales, out);
}